// Round 6
// baseline (229.464 us; speedup 1.0000x reference)
//
#include <hip/hip_runtime.h>
#include <hip/hip_bf16.h>
#include <cstdint>
#include <cstddef>

#define HID 512
#define T_SZ 4096

typedef __bf16 bf16x8 __attribute__((ext_vector_type(8)));
typedef float f32x4 __attribute__((ext_vector_type(4)));

__device__ __forceinline__ unsigned short f2bf_rne(float f) {
    unsigned int u = __float_as_uint(f);
    unsigned int r = (u + 0x7FFFu + ((u >> 16) & 1u)) >> 16;
    return (unsigned short)r;
}

__device__ __forceinline__ bf16x8 pack8(float4 x0, float4 x1) {
    bf16x8 r;
    r[0] = (__bf16)x0.x; r[1] = (__bf16)x0.y; r[2] = (__bf16)x0.z; r[3] = (__bf16)x0.w;
    r[4] = (__bf16)x1.x; r[5] = (__bf16)x1.y; r[6] = (__bf16)x1.z; r[7] = (__bf16)x1.w;
    return r;
}

__device__ __forceinline__ float fast_tanh(float x) {
    float e = __expf(2.0f * x);
    return 1.0f - 2.0f / (e + 1.0f);
}

// ---------------- kernel 1: s[b][n] = dot(dec[b,:], Ws[n,:]) ----------------
__global__ void k_s(const float* __restrict__ dec, const float* __restrict__ Ws,
                    float* __restrict__ s) {
    int idx = blockIdx.x * 256 + threadIdx.x;   // 16384 = 32*512
    int b = idx >> 9, n = idx & 511;
    const float4* dp = reinterpret_cast<const float4*>(dec + (size_t)b * HID);
    const float4* wp = reinterpret_cast<const float4*>(Ws + (size_t)n * HID);
    float acc = 0.f;
#pragma unroll 8
    for (int i = 0; i < HID / 4; ++i) {
        float4 d = dp[i], w = wp[i];
        acc += d.x * w.x + d.y * w.y + d.z * w.z + d.w * w.w;
    }
    s[idx] = acc;
}

// ------------- kernel 2: pack W_h -> bf16 fragments (kk-major) --------------
// Chunk index = kk*2048 + n4*64 + (g*16 + c); chunk (uint4) holds
// W[n4*16 + c][kk*32 + g*8 + j], j=0..7 as bf16. Lane reading chunk
// [kk*2048 + n4*64 + lane] gets its MFMA B-fragment.
__global__ void k_pack(const float* __restrict__ Wh, uint4* __restrict__ Wb) {
    int idx = blockIdx.x * 256 + threadIdx.x;   // 32768, 8 elems each
    int n = idx >> 6;
    int k0 = (idx & 63) * 8;
    const float4* p = reinterpret_cast<const float4*>(Wh + (size_t)n * HID + k0);
    float4 x0 = p[0], x1 = p[1];
    uint4 w;
    w.x = f2bf_rne(x0.x) | ((unsigned)f2bf_rne(x0.y) << 16);
    w.y = f2bf_rne(x0.z) | ((unsigned)f2bf_rne(x0.w) << 16);
    w.z = f2bf_rne(x1.x) | ((unsigned)f2bf_rne(x1.y) << 16);
    w.w = f2bf_rne(x1.z) | ((unsigned)f2bf_rne(x1.w) << 16);
    int n4 = n >> 4, c = n & 15, kk = k0 >> 5, g = (k0 >> 3) & 3;
    Wb[(size_t)kk * 2048 + n4 * 64 + g * 16 + c] = w;
}

// ------------- kernel 3: fused h = enc@Wh^T ; e_part = sum tanh(h+s).v ------
// BM=64, BN=128 (quarter of N), BK=32. 4 waves, each 64x32 output.
// A: tiny 2x4KB LDS double-buffer, reg-staged 2 steps ahead.
// B: direct global->register from L2-resident packed Wb.
//    B(kk+2) is staged AFTER the MFMAs consume B(kk) from the same parity
//    slot (round-5 bug: staging first made the MFMA read B(kk+2)).
// Barrier = lgkmcnt(0)+s_barrier only; NO vmem drain in the loop.
__global__ void __launch_bounds__(256, 4) k_gemm_e(
    const float* __restrict__ enc, const uint4* __restrict__ Wb,
    const float* __restrict__ s, const float* __restrict__ v,
    float* __restrict__ part_e) {
    __shared__ __align__(16) unsigned char Abuf[2][4096];   // 64 rows x 32 bf16
    __shared__ float red[4][64];

    const int tid = threadIdx.x;
    // bijective XCD swizzle: 8192 blocks = 8 XCD x 1024; the 4 n-strips of an
    // m-tile are adjacent logicals -> same XCD -> enc L2-shared.
    const int p = blockIdx.x;
    const int logical = (p & 7) * 1024 + (p >> 3);
    const int h = logical & 3;                  // n-strip 0..3
    const int m = logical >> 2;                 // 0..2047
    const size_t row0 = (size_t)m * 64;
    const int b = (int)(row0 >> 12);

    const int lane = tid & 63, wid = tid >> 6;
    const int c = lane & 15, g4 = lane >> 4;

    // epilogue constants (tiny, L2)
    float sv_s[2], sv_v[2];
#pragma unroll
    for (int ni = 0; ni < 2; ++ni) {
        int n = h * 128 + wid * 32 + ni * 16 + c;
        sv_s[ni] = s[b * HID + n];
        sv_v[ni] = v[n];
    }

    // A staging: thread owns chunk tid: row=(tid>>6)*16+(tid&15), k8=(tid>>4)&3
    const int arow = ((tid >> 6) << 4) + (tid & 15);
    const int ag = (tid >> 4) & 3;
    const float* Ag = enc + (row0 + arow) * HID + ag * 8;   // + kk*32
    const int abyte = tid * 16;
    // B fragment stream for this lane: + kk*2048 + ni*64 (chunks)
    const uint4* Bg = Wb + (h * 8 + wid * 2) * 64 + lane;

    float4 aR[2][2];   // staging regs, parity-indexed (static after unroll)
    uint4  bR[2][2];

    // ---- prologue: A(0) direct, A(1)->aR[1]; B(0)->bR[0], B(1)->bR[1] ----
    {
        float4 x0 = *reinterpret_cast<const float4*>(Ag);
        float4 x1 = *reinterpret_cast<const float4*>(Ag + 4);
        bR[0][0] = Bg[0];
        bR[0][1] = Bg[64];
        bR[1][0] = Bg[2048];
        bR[1][1] = Bg[2048 + 64];
        *reinterpret_cast<bf16x8*>(&Abuf[0][abyte]) = pack8(x0, x1);
        aR[1][0] = *reinterpret_cast<const float4*>(Ag + 32);
        aR[1][1] = *reinterpret_cast<const float4*>(Ag + 36);
    }
    asm volatile("s_waitcnt lgkmcnt(0)\n\ts_barrier" ::: "memory");

    f32x4 acc[4][2] = {};   // [mi][ni]

#pragma unroll
    for (int kk = 0; kk < 16; ++kk) {
        // 1) stage A(kk+2) -> aR[kk&1] (slot consumed by ds_write at kk-1)
        if (kk + 2 <= 15) {
            aR[kk & 1][0] = *reinterpret_cast<const float4*>(Ag + (kk + 2) * 32);
            aR[kk & 1][1] = *reinterpret_cast<const float4*>(Ag + (kk + 2) * 32 + 4);
        }
        // 2) ds_write A(kk+1) from regs loaded at kk-1
        if (kk + 1 <= 15)
            *reinterpret_cast<bf16x8*>(&Abuf[(kk + 1) & 1][abyte]) =
                pack8(aR[(kk + 1) & 1][0], aR[(kk + 1) & 1][1]);
        // 3) compute step kk (consumes bR[kk&1])
        bf16x8 af[4];
#pragma unroll
        for (int mi = 0; mi < 4; ++mi)
            af[mi] = *reinterpret_cast<const bf16x8*>(
                &Abuf[kk & 1][(mi * 64 + lane) * 16]);
#pragma unroll
        for (int mi = 0; mi < 4; ++mi)
#pragma unroll
            for (int ni = 0; ni < 2; ++ni)
                acc[mi][ni] = __builtin_amdgcn_mfma_f32_16x16x32_bf16(
                    af[mi], *reinterpret_cast<bf16x8*>(&bR[kk & 1][ni]),
                    acc[mi][ni], 0, 0, 0);
        // 4) stage B(kk+2) -> bR[kk&1] (slot now dead; consumed at kk+2)
        if (kk + 2 <= 15) {
            bR[kk & 1][0] = Bg[(size_t)(kk + 2) * 2048];
            bR[kk & 1][1] = Bg[(size_t)(kk + 2) * 2048 + 64];
        }
        // 5) A-dbuf handoff only: ds ops drained, vmem stays in flight
        if (kk < 15)
            asm volatile("s_waitcnt lgkmcnt(0)\n\ts_barrier" ::: "memory");
    }

    // ---- epilogue: e_part[row] += tanh(h + s[n]) * v[n] over 32 n's --------
    float e_part[4][4] = {};   // [mi][r]
#pragma unroll
    for (int ni = 0; ni < 2; ++ni) {
        float sn = sv_s[ni], vn = sv_v[ni];
#pragma unroll
        for (int mi = 0; mi < 4; ++mi)
#pragma unroll
            for (int r = 0; r < 4; ++r)
                e_part[mi][r] += fast_tanh(acc[mi][ni][r] + sn) * vn;
    }
    // reduce across the 16 n-residue lanes (bits 0..3)
#pragma unroll
    for (int mm = 1; mm <= 8; mm <<= 1)
#pragma unroll
        for (int mi = 0; mi < 4; ++mi)
#pragma unroll
            for (int r = 0; r < 4; ++r)
                e_part[mi][r] += __shfl_xor(e_part[mi][r], mm);

    if (c == 0) {
#pragma unroll
        for (int mi = 0; mi < 4; ++mi)
#pragma unroll
            for (int r = 0; r < 4; ++r)
                red[wid][mi * 16 + g4 * 4 + r] = e_part[mi][r];
    }
    __syncthreads();
    if (tid < 64)
        part_e[(size_t)h * 131072 + row0 + tid] =
            red[0][tid] + red[1][tid] + red[2][tid] + red[3][tid];
}

// ---------------- kernel 4: e = sum of 4 strips; masked softmax -> a --------
__global__ void k_softmax(const float* __restrict__ part_e, float* __restrict__ a,
                          const int* __restrict__ mask) {
    int b = blockIdx.x, tid = threadIdx.x;     // 1024 threads
    int lane = tid & 63, wid = tid >> 6;       // 16 waves
    __shared__ float red[16];
    float vals[4]; int ms[4];
    float mx = -1e30f;
#pragma unroll
    for (int j = 0; j < 4; ++j) {
        size_t t = (size_t)b * T_SZ + tid + j * 1024;
        vals[j] = part_e[t] + part_e[131072 + t] + part_e[262144 + t] + part_e[393216 + t];
        ms[j] = mask[t];
        if (ms[j]) mx = fmaxf(mx, vals[j]);
    }
#pragma unroll
    for (int m = 32; m >= 1; m >>= 1) mx = fmaxf(mx, __shfl_xor(mx, m));
    if (lane == 0) red[wid] = mx;
    __syncthreads();
    if (tid == 0) {
        float m2 = red[0];
        for (int i = 1; i < 16; ++i) m2 = fmaxf(m2, red[i]);
        red[0] = m2;
    }
    __syncthreads();
    mx = red[0];
    __syncthreads();
    float pv[4]; float sum = 0.f;
#pragma unroll
    for (int j = 0; j < 4; ++j) { pv[j] = ms[j] ? __expf(vals[j] - mx) : 0.f; sum += pv[j]; }
#pragma unroll
    for (int m = 32; m >= 1; m >>= 1) sum += __shfl_xor(sum, m);
    if (lane == 0) red[wid] = sum;
    __syncthreads();
    if (tid == 0) {
        float s2 = 0.f;
        for (int i = 0; i < 16; ++i) s2 += red[i];
        red[0] = s2;
    }
    __syncthreads();
    float inv = 1.f / red[0];
#pragma unroll
    for (int j = 0; j < 4; ++j)
        a[(size_t)b * T_SZ + tid + j * 1024] = pv[j] * inv;
}

// ---------------- kernel 5: ctx partials over T-chunks ----------------------
__global__ void k_ctx(const float* __restrict__ enc, const float* __restrict__ a,
                      float2* __restrict__ part) {
    int ts = blockIdx.x, b = blockIdx.y, tid = threadIdx.x;   // 32 x 32, 256 thr
    size_t rbase = (size_t)b * T_SZ + (size_t)ts * 128;
    const float2* ep = reinterpret_cast<const float2*>(enc + rbase * HID) + tid;
    const float* ap = a + rbase;
    float ax = 0.f, ay = 0.f, bx = 0.f, by = 0.f;
#pragma unroll 2
    for (int t = 0; t < 128; t += 2) {
        float a0 = ap[t], a1 = ap[t + 1];
        float2 e0 = ep[(size_t)t * 256], e1 = ep[(size_t)(t + 1) * 256];
        ax += a0 * e0.x; ay += a0 * e0.y;
        bx += a1 * e1.x; by += a1 * e1.y;
    }
    float2 r; r.x = ax + bx; r.y = ay + by;
    part[(size_t)(b * 32 + ts) * 256 + tid] = r;
}

// ---------------- kernel 6: reduce partials -> ctx --------------------------
__global__ void k_ctxred(const float* __restrict__ part, float* __restrict__ ctx) {
    int idx = blockIdx.x * 256 + threadIdx.x;   // 16384
    int b = idx >> 9, h = idx & 511;
    float sum = 0.f;
#pragma unroll
    for (int ts = 0; ts < 32; ++ts) sum += part[(size_t)(b * 32 + ts) * 512 + h];
    ctx[idx] = sum;
}

extern "C" void kernel_launch(void* const* d_in, const int* in_sizes, int n_in,
                              void* d_out, int out_size, void* d_ws, size_t ws_size,
                              hipStream_t stream) {
    const float* enc  = (const float*)d_in[0];   // [32,4096,512]
    const int*   mask = (const int*)d_in[1];     // [32,4096]
    const float* dec  = (const float*)d_in[2];   // [32,512]
    const float* Wh   = (const float*)d_in[3];   // [512,512]
    const float* Ws   = (const float*)d_in[4];   // [512,512]
    const float* v    = (const float*)d_in[5];   // [512]

    float* out = (float*)d_out;
    float* ctx = out;                // 16384 floats
    float* a   = out + 16384;        // 131072 floats

    // ws layout (floats): s[16384] | Wb (131072 f-slots) | part_e[524288] | part[524288]
    float* ws     = (float*)d_ws;
    float* s      = ws;
    uint4* Wb     = (uint4*)(ws + 16384);
    float* part_e = ws + 16384 + 131072;
    float* part   = part_e + 524288;

    hipLaunchKernelGGL(k_s,      dim3(64),      dim3(256),  0, stream, dec, Ws, s);
    hipLaunchKernelGGL(k_pack,   dim3(128),     dim3(256),  0, stream, Wh, Wb);
    hipLaunchKernelGGL(k_gemm_e, dim3(8192),    dim3(256),  0, stream, enc, Wb, s, v, part_e);
    hipLaunchKernelGGL(k_softmax,dim3(32),      dim3(1024), 0, stream, part_e, a, mask);
    hipLaunchKernelGGL(k_ctx,    dim3(32, 32),  dim3(256),  0, stream, enc, a, (float2*)part);
    hipLaunchKernelGGL(k_ctxred, dim3(64),      dim3(256),  0, stream, part, ctx);
}

// Round 7
// 178.551 us; speedup vs baseline: 1.2851x; 1.2851x over previous
//
#include <hip/hip_runtime.h>
#include <hip/hip_bf16.h>
#include <cstdint>
#include <cstddef>

#define HID 512
#define T_SZ 4096

typedef __bf16 bf16x8 __attribute__((ext_vector_type(8)));
typedef float f32x4 __attribute__((ext_vector_type(4)));

__device__ __forceinline__ unsigned short f2bf_rne(float f) {
    unsigned int u = __float_as_uint(f);
    unsigned int r = (u + 0x7FFFu + ((u >> 16) & 1u)) >> 16;
    return (unsigned short)r;
}

__device__ __forceinline__ bf16x8 pack8(float4 x0, float4 x1) {
    bf16x8 r;
    r[0] = (__bf16)x0.x; r[1] = (__bf16)x0.y; r[2] = (__bf16)x0.z; r[3] = (__bf16)x0.w;
    r[4] = (__bf16)x1.x; r[5] = (__bf16)x1.y; r[6] = (__bf16)x1.z; r[7] = (__bf16)x1.w;
    return r;
}

__device__ __forceinline__ float fast_tanh(float x) {
    float e = __expf(2.0f * x);
    return 1.0f - 2.0f / (e + 1.0f);
}

// ---------------- kernel 1: s[b][n] = dot(dec[b,:], Ws[n,:]) ----------------
__global__ void k_s(const float* __restrict__ dec, const float* __restrict__ Ws,
                    float* __restrict__ s) {
    int idx = blockIdx.x * 256 + threadIdx.x;   // 16384 = 32*512
    int b = idx >> 9, n = idx & 511;
    const float4* dp = reinterpret_cast<const float4*>(dec + (size_t)b * HID);
    const float4* wp = reinterpret_cast<const float4*>(Ws + (size_t)n * HID);
    float acc = 0.f;
#pragma unroll 8
    for (int i = 0; i < HID / 4; ++i) {
        float4 d = dp[i], w = wp[i];
        acc += d.x * w.x + d.y * w.y + d.z * w.z + d.w * w.w;
    }
    s[idx] = acc;
}

// ------------- kernel 2: pack W_h -> bf16 fragments (kk-major) --------------
// Chunk index = kk*2048 + n4*64 + (g*16 + c); chunk (uint4) holds
// W[n4*16 + c][kk*32 + g*8 + j], j=0..7 as bf16. Lane reading chunk
// [kk*2048 + n4*64 + lane] gets its MFMA B-fragment.
__global__ void k_pack(const float* __restrict__ Wh, uint4* __restrict__ Wb) {
    int idx = blockIdx.x * 256 + threadIdx.x;   // 32768, 8 elems each
    int n = idx >> 6;
    int k0 = (idx & 63) * 8;
    const float4* p = reinterpret_cast<const float4*>(Wh + (size_t)n * HID + k0);
    float4 x0 = p[0], x1 = p[1];
    uint4 w;
    w.x = f2bf_rne(x0.x) | ((unsigned)f2bf_rne(x0.y) << 16);
    w.y = f2bf_rne(x0.z) | ((unsigned)f2bf_rne(x0.w) << 16);
    w.z = f2bf_rne(x1.x) | ((unsigned)f2bf_rne(x1.y) << 16);
    w.w = f2bf_rne(x1.z) | ((unsigned)f2bf_rne(x1.w) << 16);
    int n4 = n >> 4, c = n & 15, kk = k0 >> 5, g = (k0 >> 3) & 3;
    Wb[(size_t)kk * 2048 + n4 * 64 + g * 16 + c] = w;
}

// ------------- kernel 3: fused h = enc@Wh^T ; e_part = sum tanh(h+s).v ------
// BM=64, BN=256 (h-half of N). Whole A tile staged ONCE (coalesced rows,
// XOR-swizzled fragment layout, 2-way max bank aliasing = free).
// K-loop: ZERO barriers; A from LDS (double-buffered regs), B from
// L2-resident Wb via a depth-3 register ring (consume slot, THEN refill).
__global__ void __launch_bounds__(256, 2) k_gemm_e(
    const float* __restrict__ enc, const uint4* __restrict__ Wb,
    const float* __restrict__ s, const float* __restrict__ v,
    float* __restrict__ part_e) {
    __shared__ __align__(16) unsigned char As[65536];   // [kk][chunk^swz] 16B
    __shared__ float red[4][64];

    const int tid = threadIdx.x;
    // bijective XCD swizzle: 4096 blocks = 8 XCD x 512; h-pairs adjacent ->
    // same XCD -> the A-tile's 2nd read is an L2 hit.
    const int p = blockIdx.x;
    const int logical = (p & 7) * 512 + (p >> 3);
    const int h = logical & 1;
    const int m = logical >> 1;                 // 0..2047
    const size_t row0 = (size_t)m * 64;
    const int b = (int)(row0 >> 12);

    const int lane = tid & 63, wid = tid >> 6;
    const int c = lane & 15, g4 = lane >> 4;

    // ---- stage full A tile, coalesced: wave i covers one 2KB row ----
    {
        const float* base = enc + row0 * HID;
#pragma unroll
        for (int i = 0; i < 16; ++i) {
            int f = i * 256 + tid;                       // chunk-of-8 index
            float4 x0 = *reinterpret_cast<const float4*>(base + (size_t)f * 8);
            float4 x1 = *reinterpret_cast<const float4*>(base + (size_t)f * 8 + 4);
            int row = f >> 6, c8 = f & 63;
            int kk = c8 >> 2, g = c8 & 3;
            int chunk = (row >> 4) * 64 + g * 16 + (row & 15);
            int byte = (kk * 4096 + chunk * 16) ^ (((((kk & 3) << 1) | (g & 1))) << 4);
            *reinterpret_cast<bf16x8*>(&As[byte]) = pack8(x0, x1);
        }
    }

    // epilogue constants
    float sv_s[4], sv_v[4];
#pragma unroll
    for (int ni = 0; ni < 4; ++ni) {
        int n = (h * 16 + wid * 4 + ni) * 16 + c;
        sv_s[ni] = s[b * HID + n];
        sv_v[ni] = v[n];
    }
    __syncthreads();   // the ONLY staging barrier

    // B fragment stream: chunk = kk*2048 + n4*64 + lane, n4 = h*16+wid*4+ni
    const uint4* Bg = Wb + (h * 16 + wid * 4) * 64 + lane;

    // depth-3 register ring for B
    uint4 bR[3][4];
#pragma unroll
    for (int d = 0; d < 3; ++d)
#pragma unroll
        for (int ni = 0; ni < 4; ++ni)
            bR[d][ni] = Bg[(size_t)d * 2048 + ni * 64];

    bf16x8 af[2][4];
#pragma unroll
    for (int mi = 0; mi < 4; ++mi) {
        int byte = ((mi * 64 + lane) * 16) ^ ((((0 & 3) << 1) | ((lane >> 4) & 1)) << 4);
        af[0][mi] = *reinterpret_cast<const bf16x8*>(&As[byte]);
    }

    f32x4 acc[4][4] = {};   // [mi][ni]

#pragma unroll
    for (int kk = 0; kk < 16; ++kk) {
        // prefetch A(kk+1) fragments from LDS (no barrier needed: tile static)
        if (kk < 15) {
#pragma unroll
            for (int mi = 0; mi < 4; ++mi) {
                int byte = ((kk + 1) * 4096 + (mi * 64 + lane) * 16)
                         ^ (((((kk + 1) & 3) << 1) | ((lane >> 4) & 1)) << 4);
                af[(kk + 1) & 1][mi] = *reinterpret_cast<const bf16x8*>(&As[byte]);
            }
        }
        // consume B slot kk%3
#pragma unroll
        for (int mi = 0; mi < 4; ++mi)
#pragma unroll
            for (int ni = 0; ni < 4; ++ni)
                acc[mi][ni] = __builtin_amdgcn_mfma_f32_16x16x32_bf16(
                    af[kk & 1][mi], *reinterpret_cast<bf16x8*>(&bR[kk % 3][ni]),
                    acc[mi][ni], 0, 0, 0);
        // refill slot kk%3 with B(kk+3) — AFTER consumption in program order
        if (kk + 3 <= 15) {
#pragma unroll
            for (int ni = 0; ni < 4; ++ni)
                bR[kk % 3][ni] = Bg[(size_t)(kk + 3) * 2048 + ni * 64];
        }
    }

    // ---- epilogue: e_part[row] += tanh(h + s[n]) * v[n] over 64 n's --------
    float e_part[4][4] = {};   // [mi][r]
#pragma unroll
    for (int ni = 0; ni < 4; ++ni) {
        float sn = sv_s[ni], vn = sv_v[ni];
#pragma unroll
        for (int mi = 0; mi < 4; ++mi)
#pragma unroll
            for (int r = 0; r < 4; ++r)
                e_part[mi][r] += fast_tanh(acc[mi][ni][r] + sn) * vn;
    }
    // reduce across the 16 n-residue lanes (bits 0..3)
#pragma unroll
    for (int mm = 1; mm <= 8; mm <<= 1)
#pragma unroll
        for (int mi = 0; mi < 4; ++mi)
#pragma unroll
            for (int r = 0; r < 4; ++r)
                e_part[mi][r] += __shfl_xor(e_part[mi][r], mm);

    if (c == 0) {
#pragma unroll
        for (int mi = 0; mi < 4; ++mi)
#pragma unroll
            for (int r = 0; r < 4; ++r)
                red[wid][mi * 16 + g4 * 4 + r] = e_part[mi][r];
    }
    __syncthreads();
    if (tid < 64)
        part_e[(size_t)h * 131072 + row0 + tid] =
            red[0][tid] + red[1][tid] + red[2][tid] + red[3][tid];
}

// ---------------- kernel 4: e = part0+part1; masked softmax -> a ------------
__global__ void k_softmax(const float* __restrict__ part_e, float* __restrict__ a,
                          const int* __restrict__ mask) {
    int b = blockIdx.x, tid = threadIdx.x;     // 1024 threads
    int lane = tid & 63, wid = tid >> 6;       // 16 waves
    __shared__ float red[16];
    float vals[4]; int ms[4];
    float mx = -1e30f;
#pragma unroll
    for (int j = 0; j < 4; ++j) {
        size_t t = (size_t)b * T_SZ + tid + j * 1024;
        vals[j] = part_e[t] + part_e[131072 + t];
        ms[j] = mask[t];
        if (ms[j]) mx = fmaxf(mx, vals[j]);
    }
#pragma unroll
    for (int m = 32; m >= 1; m >>= 1) mx = fmaxf(mx, __shfl_xor(mx, m));
    if (lane == 0) red[wid] = mx;
    __syncthreads();
    if (tid == 0) {
        float m2 = red[0];
        for (int i = 1; i < 16; ++i) m2 = fmaxf(m2, red[i]);
        red[0] = m2;
    }
    __syncthreads();
    mx = red[0];
    __syncthreads();
    float pv[4]; float sum = 0.f;
#pragma unroll
    for (int j = 0; j < 4; ++j) { pv[j] = ms[j] ? __expf(vals[j] - mx) : 0.f; sum += pv[j]; }
#pragma unroll
    for (int m = 32; m >= 1; m >>= 1) sum += __shfl_xor(sum, m);
    if (lane == 0) red[wid] = sum;
    __syncthreads();
    if (tid == 0) {
        float s2 = 0.f;
        for (int i = 0; i < 16; ++i) s2 += red[i];
        red[0] = s2;
    }
    __syncthreads();
    float inv = 1.f / red[0];
#pragma unroll
    for (int j = 0; j < 4; ++j)
        a[(size_t)b * T_SZ + tid + j * 1024] = pv[j] * inv;
}

// ---------------- kernel 5: ctx partials over T-chunks ----------------------
__global__ void k_ctx(const float* __restrict__ enc, const float* __restrict__ a,
                      float2* __restrict__ part) {
    int ts = blockIdx.x, b = blockIdx.y, tid = threadIdx.x;   // 32 x 32, 256 thr
    size_t rbase = (size_t)b * T_SZ + (size_t)ts * 128;
    const float2* ep = reinterpret_cast<const float2*>(enc + rbase * HID) + tid;
    const float* ap = a + rbase;
    float ax = 0.f, ay = 0.f, bx = 0.f, by = 0.f;
#pragma unroll 2
    for (int t = 0; t < 128; t += 2) {
        float a0 = ap[t], a1 = ap[t + 1];
        float2 e0 = ep[(size_t)t * 256], e1 = ep[(size_t)(t + 1) * 256];
        ax += a0 * e0.x; ay += a0 * e0.y;
        bx += a1 * e1.x; by += a1 * e1.y;
    }
    float2 r; r.x = ax + bx; r.y = ay + by;
    part[(size_t)(b * 32 + ts) * 256 + tid] = r;
}

// ---------------- kernel 6: reduce partials -> ctx --------------------------
__global__ void k_ctxred(const float* __restrict__ part, float* __restrict__ ctx) {
    int idx = blockIdx.x * 256 + threadIdx.x;   // 16384
    int b = idx >> 9, h = idx & 511;
    float sum = 0.f;
#pragma unroll
    for (int ts = 0; ts < 32; ++ts) sum += part[(size_t)(b * 32 + ts) * 512 + h];
    ctx[idx] = sum;
}

extern "C" void kernel_launch(void* const* d_in, const int* in_sizes, int n_in,
                              void* d_out, int out_size, void* d_ws, size_t ws_size,
                              hipStream_t stream) {
    const float* enc  = (const float*)d_in[0];   // [32,4096,512]
    const int*   mask = (const int*)d_in[1];     // [32,4096]
    const float* dec  = (const float*)d_in[2];   // [32,512]
    const float* Wh   = (const float*)d_in[3];   // [512,512]
    const float* Ws   = (const float*)d_in[4];   // [512,512]
    const float* v    = (const float*)d_in[5];   // [512]

    float* out = (float*)d_out;
    float* ctx = out;                // 16384 floats
    float* a   = out + 16384;        // 131072 floats

    // ws layout (floats): s[16384] | Wb (131072 f-slots) | part_e[262144] | part[524288]
    float* ws     = (float*)d_ws;
    float* s      = ws;
    uint4* Wb     = (uint4*)(ws + 16384);
    float* part_e = ws + 16384 + 131072;
    float* part   = part_e + 262144;

    hipLaunchKernelGGL(k_s,      dim3(64),      dim3(256),  0, stream, dec, Ws, s);
    hipLaunchKernelGGL(k_pack,   dim3(128),     dim3(256),  0, stream, Wh, Wb);
    hipLaunchKernelGGL(k_gemm_e, dim3(4096),    dim3(256),  0, stream, enc, Wb, s, v, part_e);
    hipLaunchKernelGGL(k_softmax,dim3(32),      dim3(1024), 0, stream, part_e, a, mask);
    hipLaunchKernelGGL(k_ctx,    dim3(32, 32),  dim3(256),  0, stream, enc, a, (float2*)part);
    hipLaunchKernelGGL(k_ctxred, dim3(64),      dim3(256),  0, stream, part, ctx);
}